// Round 1
// baseline (638.650 us; speedup 1.0000x reference)
//
#include <hip/hip_runtime.h>
#include <hip/hip_bf16.h>

#define SQRT2C 1.41421356237309515f
#define LEAKF 0.2f

typedef __attribute__((ext_vector_type(4))) float f32x4;
typedef __attribute__((ext_vector_type(8))) __bf16 bf16x8;

#define GLOAD16(g, l) \
  __builtin_amdgcn_global_load_lds((const __attribute__((address_space(1))) void*)(const void*)(g), \
                                   (__attribute__((address_space(3))) void*)(void*)(l), 16, 0, 0)

__device__ __forceinline__ unsigned short f2bf(float f) {
  unsigned int u = __float_as_uint(f);
  unsigned int r = (u + 0x7fffu + ((u >> 16) & 1u)) >> 16;
  return (unsigned short)r;
}

// ---------------- s = w @ aff_w.T + aff_b + 1 ----------------
__global__ void k_affine(const float* __restrict__ w, const float* __restrict__ aw,
                         const float* __restrict__ ab, float* __restrict__ s, int C) {
  int wid = (blockIdx.x * blockDim.x + threadIdx.x) >> 6;
  int lane = threadIdx.x & 63;
  int b = wid / C, i = wid % C;
  const float* wr = w + (size_t)b * 512;
  const float* ar = aw + (size_t)i * 512;
  float acc = 0.f;
  #pragma unroll
  for (int l = 0; l < 512; l += 64) acc += wr[l + lane] * ar[l + lane];
  #pragma unroll
  for (int off = 32; off; off >>= 1) acc += __shfl_down(acc, off, 64);
  if (lane == 0) s[wid] = acc + ab[i] + 1.0f;
}

// ---------------- d[b,o] = rsqrt(sum_i s^2 * sum_tap w^2 + 1e-8) ----------------
__global__ void k_demod(const float* __restrict__ weight, const float* __restrict__ s,
                        float* __restrict__ d, int CIN) {
  int o = blockIdx.x & 255, b = blockIdx.x >> 8;
  int t = threadIdx.x;
  const float* wr = weight + (size_t)o * CIN * 9;
  const float* sr = s + (size_t)b * CIN;
  float acc = 0.f;
  for (int i = t; i < CIN; i += 256) {
    float sv = sr[i];
    float ws = 0.f;
    #pragma unroll
    for (int k = 0; k < 9; ++k) { float w = wr[(size_t)i * 9 + k]; ws += w * w; }
    acc += sv * sv * ws;
  }
  __shared__ float red[256];
  red[t] = acc; __syncthreads();
  for (int h = 128; h; h >>= 1) { if (t < h) red[t] += red[t + h]; __syncthreads(); }
  if (t == 0) d[blockIdx.x] = rsqrtf(red[0] + 1e-8f);
}

// T matrices for fused transpose-conv + blur (per output parity)
__device__ __constant__ float Tm[2][3][3] = {
  {{0.f,1.f,3.f},{3.f,3.f,1.f},{1.f,0.f,0.f}},
  {{0.f,0.f,1.f},{1.f,3.f,3.f},{3.f,1.f,0.f}}
};

// ---------------- W1eff[b][rho][tap][o][i] (bf16) ----------------
__global__ void k_weff1(const float* __restrict__ w1, const float* __restrict__ s1,
                        const float* __restrict__ d1, unsigned short* __restrict__ We) {
  int t = blockIdx.x * 256 + threadIdx.x;   // 8*256*512 threads
  int i = t & 511, o = (t >> 9) & 255, b = t >> 17;
  float sd = s1[b * 512 + i] * d1[b * 256 + o];
  const float* wp = w1 + ((size_t)o * 512 + i) * 9;
  float wm[3][3];
  #pragma unroll
  for (int ky = 0; ky < 3; ++ky)
    #pragma unroll
    for (int kx = 0; kx < 3; ++kx) wm[ky][kx] = wp[ky * 3 + kx] * sd;
  #pragma unroll
  for (int ry = 0; ry < 2; ++ry) {
    float tmp[3][3];  // [u][kx]
    #pragma unroll
    for (int u = 0; u < 3; ++u)
      #pragma unroll
      for (int kx = 0; kx < 3; ++kx)
        tmp[u][kx] = Tm[ry][u][0] * wm[0][kx] + Tm[ry][u][1] * wm[1][kx] + Tm[ry][u][2] * wm[2][kx];
    #pragma unroll
    for (int rx = 0; rx < 2; ++rx)
      #pragma unroll
      for (int u = 0; u < 3; ++u)
        #pragma unroll
        for (int v = 0; v < 3; ++v) {
          float val = (Tm[rx][v][0] * tmp[u][0] + Tm[rx][v][1] * tmp[u][1] + Tm[rx][v][2] * tmp[u][2]) * 0.0625f;
          We[(((size_t)(b * 4 + ry * 2 + rx) * 9) + u * 3 + v) * 131072 + (size_t)o * 512 + i] = f2bf(val);
        }
  }
}

// ---------------- W2m[b][tap][o][i] (bf16) ----------------
__global__ void k_weff2(const float* __restrict__ w2, const float* __restrict__ s2,
                        const float* __restrict__ d2, unsigned short* __restrict__ Wm) {
  int t = blockIdx.x * 256 + threadIdx.x;   // 8*256*256 threads
  int i = t & 255, o = (t >> 8) & 255, b = t >> 16;
  float sd = s2[b * 256 + i] * d2[b * 256 + o];
  const float* wp = w2 + ((size_t)o * 256 + i) * 9;
  #pragma unroll
  for (int k = 0; k < 9; ++k)
    Wm[((size_t)(b * 9 + k) * 256 + o) * 256 + i] = f2bf(wp[k] * sd);
}

// ---------------- zero fill (uint4) ----------------
__global__ void k_fill0(uint4* __restrict__ p, int n4) {
  int t = blockIdx.x * 256 + threadIdx.x;
  if (t < n4) p[t] = make_uint4(0u, 0u, 0u, 0u);
}

// ---------------- x [8][512][64][64] f32 -> xt [8][66][66][512] bf16 (halo interior) ----------------
__global__ void k_txpose(const float* __restrict__ x, unsigned short* __restrict__ xt) {
  int bid = blockIdx.x;            // 8192 = b(8) * y(64) * x0(2) * i0(8)
  int i0 = (bid & 7) * 64;
  int x0 = ((bid >> 3) & 1) * 32;
  int y  = (bid >> 4) & 63;
  int b  = bid >> 10;
  int tx = threadIdx.x & 31, ty = threadIdx.x >> 5;
  __shared__ float tile[64][33];
  const float* xp = x + ((size_t)(b * 512 + i0) * 64 + y) * 64 + x0;
  for (int ii = ty; ii < 64; ii += 8) tile[ii][tx] = xp[(size_t)ii * 4096 + tx];
  __syncthreads();
  unsigned short* op = xt + (((size_t)(b * 66) + y + 1) * 66 + x0 + 1) * 512 + i0;
  for (int xx = ty; xx < 32; xx += 8) {
    int iL = tx * 2;
    unsigned int pk = (unsigned int)f2bf(tile[iL][xx]) | ((unsigned int)f2bf(tile[iL + 1][xx]) << 16);
    *(unsigned int*)&op[(size_t)xx * 512 + iL] = pk;
  }
}

// ---------------- implicit-GEMM conv (m97 structure): C[o][pix] = sum_tap sum_i W*X ----------------
template<int CIN, int GRID, int GSH, int HP, int RHO_N, bool CONV2>
__global__ __launch_bounds__(256) void k_conv(
    const unsigned short* __restrict__ Xt,   // [8][HP][HP][CIN] bf16 (zero halo)
    const unsigned short* __restrict__ Wt,   // [8*RHO_N*9][256][CIN] bf16
    const float* __restrict__ noise,         // [8][128][128]
    const float* __restrict__ nsp,           // scalar
    const float* __restrict__ bias,          // [256]
    unsigned short* __restrict__ Yb,         // conv1 out: [8][130][130][256] bf16
    float* __restrict__ Yf)                  // conv2 out: [8][256][128][128] f32
{
  constexpr int NT = (GRID * GRID) / 128;
  constexpr size_t WPL = (size_t)256 * CIN;
  int bid = blockIdx.x;
  int nt = bid % NT;
  int mt = (bid / NT) & 1;
  int rho = (bid / (NT * 2)) % RHO_N;
  int b = bid / (NT * 2 * RHO_N);
  int o0 = mt * 128, pix0 = nt * 128;
  int tid = threadIdx.x, lane = tid & 63, wave = tid >> 6;

  __shared__ unsigned short Als[128 * 64];
  __shared__ unsigned short Bls[128 * 64];

  int rowIdx = wave * 8 + (lane >> 3);
  int colk = (lane & 7) * 8;

  const unsigned short* Wbase = Wt + (size_t)((b * RHO_N + rho) * 9) * WPL
                                + (size_t)(o0 + rowIdx) * CIN + colk;
  size_t xb[4];
  #pragma unroll
  for (int it = 0; it < 4; ++it) {
    int pix = pix0 + it * 32 + rowIdx;
    int gy = pix >> GSH, gx = pix & (GRID - 1);
    xb[it] = (((size_t)b * HP + gy) * HP + gx) * CIN + colk;
  }
  unsigned short* AlsW = &Als[(wave * 8) * 64];
  unsigned short* BlsW = &Bls[(wave * 8) * 64];

  f32x4 acc[4][4];
  #pragma unroll
  for (int m = 0; m < 4; ++m)
    #pragma unroll
    for (int n = 0; n < 4; ++n) acc[m][n] = (f32x4){0.f, 0.f, 0.f, 0.f};

  int wr = wave >> 1, wc = wave & 1;
  int lr = lane & 15, lq = lane >> 4;
  const unsigned short* Ard = &Als[(wr * 64 + lr) * 64 + lq * 8];
  const unsigned short* Brd = &Bls[(wc * 64 + lr) * 64 + lq * 8];

  for (int tap = 0; tap < 9; ++tap) {
    size_t toff = ((size_t)(tap / 3) * HP + (tap % 3)) * CIN;
    const unsigned short* Wtap = Wbase + (size_t)tap * WPL;
    for (int icc = 0; icc < CIN / 64; ++icc) {
      int ko = icc * 64;
      #pragma unroll
      for (int it = 0; it < 4; ++it) {
        GLOAD16(Wtap + (size_t)it * 32 * CIN + ko, AlsW + it * 32 * 64);
        GLOAD16(Xt + xb[it] + toff + ko, BlsW + it * 32 * 64);
      }
      __syncthreads();
      #pragma unroll
      for (int kk = 0; kk < 64; kk += 32) {
        bf16x8 af[4], bv[4];
        #pragma unroll
        for (int m = 0; m < 4; ++m) af[m] = *(const bf16x8*)&Ard[m * 16 * 64 + kk];
        #pragma unroll
        for (int n = 0; n < 4; ++n) bv[n] = *(const bf16x8*)&Brd[n * 16 * 64 + kk];
        #pragma unroll
        for (int m = 0; m < 4; ++m)
          #pragma unroll
          for (int n = 0; n < 4; ++n)
            acc[m][n] = __builtin_amdgcn_mfma_f32_16x16x32_bf16(af[m], bv[n], acc[m][n], 0, 0, 0);
      }
      __syncthreads();
    }
  }

  // epilogue: + ns*noise + bias, leaky-relu * sqrt(2)
  float ns = nsp[0];
  int ry = (RHO_N == 4) ? (rho >> 1) : 0;
  int rx = (RHO_N == 4) ? (rho & 1) : 0;
  #pragma unroll
  for (int m = 0; m < 4; ++m) {
    int o = o0 + wr * 64 + m * 16 + lq * 4;
    #pragma unroll
    for (int n = 0; n < 4; ++n) {
      int pix = pix0 + wc * 64 + n * 16 + lr;
      int p, q;
      if (CONV2) { p = pix >> 7; q = pix & 127; }
      else       { p = ((pix >> 6) << 1) + ry; q = ((pix & 63) << 1) + rx; }
      float nz = ns * noise[((size_t)b << 14) + (p << 7) + q];
      if (CONV2) {
        #pragma unroll
        for (int r = 0; r < 4; ++r) {
          float v = acc[m][n][r] + nz + bias[o + r];
          v = (v >= 0.f ? v : LEAKF * v) * SQRT2C;
          Yf[(((size_t)b * 256 + o + r) << 14) + (p << 7) + q] = v;
        }
      } else {
        ushort4 pk;
        #pragma unroll
        for (int r = 0; r < 4; ++r) {
          float v = acc[m][n][r] + nz + bias[o + r];
          v = (v >= 0.f ? v : LEAKF * v) * SQRT2C;
          ((unsigned short*)&pk)[r] = f2bf(v);
        }
        *(ushort4*)&Yb[(((size_t)(b * 130) + p + 1) * 130 + q + 1) * 256 + o] = pk;
      }
    }
  }
}

extern "C" void kernel_launch(void* const* d_in, const int* in_sizes, int n_in,
                              void* d_out, int out_size, void* d_ws, size_t ws_size,
                              hipStream_t stream) {
  (void)in_sizes; (void)n_in; (void)out_size; (void)ws_size;
  const float* x       = (const float*)d_in[0];
  const float* w1      = (const float*)d_in[1];
  const float* w2      = (const float*)d_in[2];
  const float* noise1  = (const float*)d_in[3];
  const float* noise2  = (const float*)d_in[4];
  const float* weight1 = (const float*)d_in[5];
  const float* aff1w   = (const float*)d_in[6];
  const float* aff1b   = (const float*)d_in[7];
  const float* weight2 = (const float*)d_in[8];
  const float* aff2w   = (const float*)d_in[9];
  const float* aff2b   = (const float*)d_in[10];
  const float* ns1     = (const float*)d_in[11];
  const float* ns2     = (const float*)d_in[12];
  const float* b1      = (const float*)d_in[13];
  const float* b2      = (const float*)d_in[14];

  char* ws = (char*)d_ws;
  float* s1 = (float*)(ws + 0);
  float* s2 = (float*)(ws + 16384);
  float* d1 = (float*)(ws + 24576);
  float* d2 = (float*)(ws + 32768);
  unsigned short* xt  = (unsigned short*)(ws + 40960);        // 8*66*66*512 bf16
  unsigned short* y1p = (unsigned short*)(ws + 35725312);     // 8*130*130*256 bf16
  unsigned short* W1e = (unsigned short*)(ws + 104947712);    // 8*4*9*256*512 bf16
  unsigned short* W2m = (unsigned short*)(ws + 180445184);    // 8*9*256*256 bf16

  k_affine<<<1024, 256, 0, stream>>>(w1, aff1w, aff1b, s1, 512);
  k_affine<<<512,  256, 0, stream>>>(w2, aff2w, aff2b, s2, 256);
  k_demod<<<2048, 256, 0, stream>>>(weight1, s1, d1, 512);
  k_demod<<<2048, 256, 0, stream>>>(weight2, s2, d2, 256);
  k_weff1<<<4096, 256, 0, stream>>>(weight1, s1, d1, W1e);
  k_weff2<<<2048, 256, 0, stream>>>(weight2, s2, d2, W2m);
  k_fill0<<<(2230272 + 255) / 256, 256, 0, stream>>>((uint4*)xt, 2230272);
  k_txpose<<<8192, 256, 0, stream>>>(x, xt);
  k_fill0<<<(4326400 + 255) / 256, 256, 0, stream>>>((uint4*)y1p, 4326400);
  k_conv<512, 64, 6, 66, 4, false><<<2048, 256, 0, stream>>>(xt, W1e, noise1, ns1, b1, y1p, nullptr);
  k_conv<256, 128, 7, 130, 1, true><<<2048, 256, 0, stream>>>(y1p, W2m, noise2, ns2, b2, nullptr, (float*)d_out);
}